// Round 3
// baseline (130.578 us; speedup 1.0000x reference)
//
#include <hip/hip_runtime.h>
#include <hip/hip_bf16.h>
#include <math.h>

#define B_ROWS 4096
#define N_ROWS 8192
#define D 128
#define NT 64  // 128-row tiles

typedef __attribute__((ext_vector_type(8))) short bf16x8;
typedef __attribute__((ext_vector_type(4))) float f32x4;

#if __has_builtin(__builtin_amdgcn_exp2f)
#define EXP2(x) __builtin_amdgcn_exp2f(x)
#else
#define EXP2(x) exp2f(x)
#endif
#define K2 2.8853900818f  // 2 * log2(e): exp(2c) = 2^(c*K2)

// ---- Kernel 1: normalize pair (r, r+B) in one wave; exact fp32 positive ----
__global__ __launch_bounds__(256) void normalize_pos_kernel(
    const float* __restrict__ z_i, const float* __restrict__ z_j,
    ushort* __restrict__ Z, float* __restrict__ pos_buf) {
  const int wave = threadIdx.x >> 6;
  const int lane = threadIdx.x & 63;
  const int r = blockIdx.x * 4 + wave;
  float2 vi = *(const float2*)(z_i + (size_t)r * D + lane * 2);
  float2 vj = *(const float2*)(z_j + (size_t)r * D + lane * 2);
  float ssi = vi.x * vi.x + vi.y * vi.y;
  float ssj = vj.x * vj.x + vj.y * vj.y;
  float cr = vi.x * vj.x + vi.y * vj.y;
#pragma unroll
  for (int off = 32; off > 0; off >>= 1) {
    ssi += __shfl_xor(ssi, off);
    ssj += __shfl_xor(ssj, off);
    cr += __shfl_xor(cr, off);
  }
  float si = 1.0f / fmaxf(sqrtf(ssi), 1e-12f);
  float sj = 1.0f / fmaxf(sqrtf(ssj), 1e-12f);
  __hip_bfloat16 a0 = __float2bfloat16(vi.x * si);
  __hip_bfloat16 a1 = __float2bfloat16(vi.y * si);
  __hip_bfloat16 b0 = __float2bfloat16(vj.x * sj);
  __hip_bfloat16 b1 = __float2bfloat16(vj.y * sj);
  ushort2 oi, oj;
  oi.x = *(ushort*)&a0; oi.y = *(ushort*)&a1;
  oj.x = *(ushort*)&b0; oj.y = *(ushort*)&b1;
  *(ushort2*)(Z + (size_t)r * D + lane * 2) = oi;
  *(ushort2*)(Z + (size_t)(r + B_ROWS) * D + lane * 2) = oj;
  if (lane == 0) {
    float pos = 2.0f * cr * si * sj;  // exact fp32 positive logit
    pos_buf[r] = pos;
    pos_buf[r + B_ROWS] = pos;
  }
}

// ---- Kernel 2: symmetric exp-rowsum over upper-triangle 128x128 tiles ----
// grid (64,64); ti=bx, tj=by, exit if ti>tj. 4 waves in 2x2 (wy=rows, wx=cols).
// partials layout: [64][8192] (k-major) -> coalesced writes, coalesced fin reads.
__global__ __launch_bounds__(256) void sim_kernel(
    const ushort* __restrict__ Z, float* __restrict__ partials) {
  const int ti = blockIdx.x, tj = blockIdx.y;
  if (ti > tj) return;
  const bool isdiag = (ti == tj);
  const int t = threadIdx.x;
  const int lane = t & 63;
  const int w = t >> 6;
  const int wy = w >> 1, wx = w & 1;
  const int l15 = lane & 15;
  const int l4 = lane >> 4;  // 0..3

  // A fragments: rows ti*128 + wy*64 + rs*16 + l15, k = ks*32 + l4*8
  bf16x8 a[4][4];
  const int arow = ti * 128 + wy * 64 + l15;
#pragma unroll
  for (int rs = 0; rs < 4; ++rs)
#pragma unroll
    for (int ks = 0; ks < 4; ++ks)
      a[rs][ks] = *(const bf16x8*)(Z + (size_t)(arow + rs * 16) * D + ks * 32 + l4 * 8);

  float rowacc[4][4];
#pragma unroll
  for (int rs = 0; rs < 4; ++rs)
#pragma unroll
    for (int r = 0; r < 4; ++r) rowacc[rs][r] = 0.f;
  float colacc[4] = {0.f, 0.f, 0.f, 0.f};

#pragma unroll
  for (int cs = 0; cs < 4; ++cs) {
    const int bcol = tj * 128 + wx * 64 + cs * 16 + l15;
    bf16x8 b[4];
#pragma unroll
    for (int ks = 0; ks < 4; ++ks)
      b[ks] = *(const bf16x8*)(Z + (size_t)bcol * D + ks * 32 + l4 * 8);

    f32x4 c[4];
#pragma unroll
    for (int rs = 0; rs < 4; ++rs) c[rs] = (f32x4){0.f, 0.f, 0.f, 0.f};
#pragma unroll
    for (int ks = 0; ks < 4; ++ks)
#pragma unroll
      for (int rs = 0; rs < 4; ++rs)
        c[rs] = __builtin_amdgcn_mfma_f32_16x16x32_bf16(a[rs][ks], b[ks], c[rs], 0, 0, 0);

    if (isdiag) {
      // mask gi==gj; no col path needed (cols covered by this tile's rows)
      const int gj = tj * 128 + wx * 64 + cs * 16 + l15;
#pragma unroll
      for (int rs = 0; rs < 4; ++rs) {
        const int gibase = ti * 128 + wy * 64 + rs * 16 + l4 * 4;
#pragma unroll
        for (int reg = 0; reg < 4; ++reg) {
          float e = EXP2(c[rs][reg] * K2);
          rowacc[rs][reg] += (gibase + reg != gj) ? e : 0.f;
        }
      }
    } else {
      float coltmp = 0.f;
#pragma unroll
      for (int rs = 0; rs < 4; ++rs)
#pragma unroll
        for (int reg = 0; reg < 4; ++reg) {
          float e = EXP2(c[rs][reg] * K2);
          rowacc[rs][reg] += e;
          coltmp += e;
        }
      // reduce over the 4 l4 row-groups -> full 64-row column sum
      coltmp += __shfl_xor(coltmp, 16);
      coltmp += __shfl_xor(coltmp, 32);
      colacc[cs] = coltmp;
    }
  }

  // reduce rowacc across the 16 column-lanes
#pragma unroll
  for (int rs = 0; rs < 4; ++rs)
#pragma unroll
    for (int r = 0; r < 4; ++r) {
      float v = rowacc[rs][r];
      v += __shfl_xor(v, 1);
      v += __shfl_xor(v, 2);
      v += __shfl_xor(v, 4);
      v += __shfl_xor(v, 8);
      rowacc[rs][r] = v;
    }

  __shared__ float rowled[128];
  __shared__ float colled[128];
  // phase 1: wx==0 waves own rowled; wy==0 waves own colled
  if (wx == 0 && l15 == 0) {
#pragma unroll
    for (int rs = 0; rs < 4; ++rs)
#pragma unroll
      for (int r = 0; r < 4; ++r)
        rowled[wy * 64 + rs * 16 + l4 * 4 + r] = rowacc[rs][r];
  }
  if (!isdiag && wy == 0 && l4 == 0) {
#pragma unroll
    for (int cs = 0; cs < 4; ++cs) colled[wx * 64 + cs * 16 + l15] = colacc[cs];
  }
  __syncthreads();
  // phase 2: the partner waves add
  if (wx == 1 && l15 == 0) {
#pragma unroll
    for (int rs = 0; rs < 4; ++rs)
#pragma unroll
      for (int r = 0; r < 4; ++r)
        rowled[wy * 64 + rs * 16 + l4 * 4 + r] += rowacc[rs][r];
  }
  if (!isdiag && wy == 1 && l4 == 0) {
#pragma unroll
    for (int cs = 0; cs < 4; ++cs) colled[wx * 64 + cs * 16 + l15] += colacc[cs];
  }
  __syncthreads();

  if (t < 128)
    partials[(size_t)tj * N_ROWS + ti * 128 + t] = rowled[t];
  else if (!isdiag)
    partials[(size_t)ti * N_ROWS + tj * 128 + (t - 128)] = colled[t - 128];
}

// ---- Kernel 3: per-row lse term, block partial sums ----
__global__ __launch_bounds__(128) void fin1_kernel(
    const float* __restrict__ partials, const float* __restrict__ pos_buf,
    float* __restrict__ loss_part) {
  const int row = blockIdx.x * 128 + threadIdx.x;
  float tot = 0.f;
#pragma unroll
  for (int k = 0; k < NT; ++k) tot += partials[(size_t)k * N_ROWS + row];
  float term = __logf(tot) - pos_buf[row];
#pragma unroll
  for (int off = 32; off > 0; off >>= 1) term += __shfl_xor(term, off);
  __shared__ float wsum[2];
  if ((threadIdx.x & 63) == 0) wsum[threadIdx.x >> 6] = term;
  __syncthreads();
  if (threadIdx.x == 0) loss_part[blockIdx.x] = wsum[0] + wsum[1];
}

// ---- Kernel 4: final 64 -> 1 ----
__global__ __launch_bounds__(64) void fin2_kernel(
    const float* __restrict__ loss_part, float* __restrict__ out) {
  float v = loss_part[threadIdx.x];
#pragma unroll
  for (int off = 32; off > 0; off >>= 1) v += __shfl_xor(v, off);
  if (threadIdx.x == 0) out[0] = v / (float)N_ROWS;
}

extern "C" void kernel_launch(void* const* d_in, const int* in_sizes, int n_in,
                              void* d_out, int out_size, void* d_ws, size_t ws_size,
                              hipStream_t stream) {
  const float* z_i = (const float*)d_in[0];
  const float* z_j = (const float*)d_in[1];
  float* out = (float*)d_out;

  ushort* Z = (ushort*)d_ws;                                        // 2 MB
  float* partials = (float*)((char*)d_ws + (size_t)N_ROWS * D * 2); // 2 MB
  float* pos_buf = partials + (size_t)NT * N_ROWS;                  // 32 KB
  float* loss_part = pos_buf + N_ROWS;

  hipLaunchKernelGGL(normalize_pos_kernel, dim3(B_ROWS / 4), dim3(256), 0,
                     stream, z_i, z_j, Z, pos_buf);
  hipLaunchKernelGGL(sim_kernel, dim3(NT, NT), dim3(256), 0, stream, Z,
                     partials);
  hipLaunchKernelGGL(fin1_kernel, dim3(N_ROWS / 128), dim3(128), 0, stream,
                     partials, pos_buf, loss_part);
  hipLaunchKernelGGL(fin2_kernel, dim3(1), dim3(64), 0, stream, loss_part, out);
}

// Round 4
// 112.618 us; speedup vs baseline: 1.1595x; 1.1595x over previous
//
#include <hip/hip_runtime.h>
#include <hip/hip_bf16.h>
#include <math.h>

#define B_ROWS 4096
#define N_ROWS 8192
#define D 128
#define NT 64     // number of 128-row tiles
#define SEGS 13   // 65 j-tiles per super-row = 13 segs x 5 tiles
#define TPS 5
#define K2 2.8853900818f  // 2*log2(e): exp(2c) = 2^(c*K2)

#define CHUNK_STRIDE 1056          // 1024 B data (4 rows) + 32 B pad
#define BS_BYTES (32 * CHUNK_STRIDE)

typedef __attribute__((ext_vector_type(8))) short bf16x8;
typedef __attribute__((ext_vector_type(4))) float f32x4;

#if __has_builtin(__builtin_amdgcn_exp2f)
#define EXP2(x) __builtin_amdgcn_exp2f(x)
#else
#define EXP2(x) exp2f(x)
#endif

__device__ __forceinline__ void async_copy_1k(void* lds_dst, const void* g_src_lane) {
  __builtin_amdgcn_global_load_lds(
      (const __attribute__((address_space(1))) void*)g_src_lane,
      (__attribute__((address_space(3))) void*)lds_dst, 16, 0, 0);
}

// ---- Kernel 1: normalize pair (r, r+B); exact fp32 positive; zero out ----
__global__ __launch_bounds__(256) void normalize_pos_kernel(
    const float* __restrict__ z_i, const float* __restrict__ z_j,
    ushort* __restrict__ Z, float* __restrict__ pos_buf,
    float* __restrict__ out) {
  if (blockIdx.x == 0 && threadIdx.x == 0) out[0] = 0.f;
  const int wave = threadIdx.x >> 6;
  const int lane = threadIdx.x & 63;
  const int r = blockIdx.x * 4 + wave;
  float2 vi = *(const float2*)(z_i + (size_t)r * D + lane * 2);
  float2 vj = *(const float2*)(z_j + (size_t)r * D + lane * 2);
  float ssi = vi.x * vi.x + vi.y * vi.y;
  float ssj = vj.x * vj.x + vj.y * vj.y;
  float cr = vi.x * vj.x + vi.y * vj.y;
#pragma unroll
  for (int off = 32; off > 0; off >>= 1) {
    ssi += __shfl_xor(ssi, off);
    ssj += __shfl_xor(ssj, off);
    cr += __shfl_xor(cr, off);
  }
  float si = 1.0f / fmaxf(sqrtf(ssi), 1e-12f);
  float sj = 1.0f / fmaxf(sqrtf(ssj), 1e-12f);
  __hip_bfloat16 a0 = __float2bfloat16(vi.x * si);
  __hip_bfloat16 a1 = __float2bfloat16(vi.y * si);
  __hip_bfloat16 b0 = __float2bfloat16(vj.x * sj);
  __hip_bfloat16 b1 = __float2bfloat16(vj.y * sj);
  ushort2 oi, oj;
  oi.x = *(ushort*)&a0; oi.y = *(ushort*)&a1;
  oj.x = *(ushort*)&b0; oj.y = *(ushort*)&b1;
  *(ushort2*)(Z + (size_t)r * D + lane * 2) = oi;
  *(ushort2*)(Z + (size_t)(r + B_ROWS) * D + lane * 2) = oj;
  if (lane == 0) {
    float pos = 2.0f * cr * si * sj;
    pos_buf[r] = pos;
    pos_buf[r + B_ROWS] = pos;
  }
}

// ---- Kernel 2: symmetric exp-rowsum, balanced strips, LDS-staged B ----
// Super-row bi pairs row-tiles (bi) and (63-bi): 65 j-tiles total, split into
// 13 segments of 5. A fragments in registers; B tiles async-staged to LDS.
__global__ __launch_bounds__(256, 3) void sim_kernel(
    const ushort* __restrict__ Z, float* __restrict__ partials) {
  __shared__ __align__(16) char Bs[BS_BYTES];
  __shared__ float rowled[128];
  __shared__ float colled[128];
  const int t = threadIdx.x;
  const int lane = t & 63;
  const int w = t >> 6;
  const int wy = w >> 1, wx = w & 1;
  const int l15 = lane & 15;
  const int l4 = lane >> 4;  // 0..3
  const int seg = blockIdx.x;  // 0..12
  const int bi = blockIdx.y;   // 0..31
  const int len1 = NT - bi;

  // per-thread LDS byte offset for B-fragment reads (row cs*16+l15, k l4*8)
  const int brow_off = (l15 >> 2) * CHUNK_STRIDE + (l15 & 3) * 256 + l4 * 16;

  bf16x8 a[4][4];
  int cur_ti = -1;

  for (int it = 0; it < TPS; ++it) {
    const int p = seg * TPS + it;
    int ti, jt;
    if (p < len1) { ti = bi; jt = bi + p; }
    else { ti = NT - 1 - bi; jt = ti + (p - len1); }
    const bool isdiag = (ti == jt);

    if (ti != cur_ti) {  // wave-uniform; at most twice per block
      cur_ti = ti;
      const int arow = ti * 128 + wy * 64 + l15;
#pragma unroll
      for (int rs = 0; rs < 4; ++rs)
#pragma unroll
        for (int ks = 0; ks < 4; ++ks)
          a[rs][ks] = *(const bf16x8*)(Z + (size_t)(arow + rs * 16) * D + ks * 32 + l4 * 8);
    }

    // async-stage B tile jt (32 KB): wave w copies chunks 8w..8w+7
    {
      const char* gbase = (const char*)Z + (size_t)jt * 128 * (D * 2);
#pragma unroll
      for (int q = 0; q < 8; ++q) {
        const int c = w * 8 + q;
        async_copy_1k(Bs + c * CHUNK_STRIDE, gbase + c * 1024 + lane * 16);
      }
    }
    __syncthreads();  // drains glds (vmcnt) + protects Bs reuse

    float rowacc[4][4];
#pragma unroll
    for (int rs = 0; rs < 4; ++rs)
#pragma unroll
      for (int r = 0; r < 4; ++r) rowacc[rs][r] = 0.f;
    float colacc[4] = {0.f, 0.f, 0.f, 0.f};

#pragma unroll
    for (int cs = 0; cs < 4; ++cs) {
      bf16x8 b[4];
#pragma unroll
      for (int ks = 0; ks < 4; ++ks)
        b[ks] = *(const bf16x8*)(Bs + cs * (4 * CHUNK_STRIDE) + brow_off + ks * 64);

      f32x4 c[4];
#pragma unroll
      for (int rs = 0; rs < 4; ++rs) c[rs] = (f32x4){0.f, 0.f, 0.f, 0.f};
#pragma unroll
      for (int ks = 0; ks < 4; ++ks)
#pragma unroll
        for (int rs = 0; rs < 4; ++rs)
          c[rs] = __builtin_amdgcn_mfma_f32_16x16x32_bf16(a[rs][ks], b[ks], c[rs], 0, 0, 0);

      if (isdiag) {
        const int gj = jt * 128 + wx * 64 + cs * 16 + l15;
#pragma unroll
        for (int rs = 0; rs < 4; ++rs) {
          const int gibase = ti * 128 + wy * 64 + rs * 16 + l4 * 4;
#pragma unroll
          for (int reg = 0; reg < 4; ++reg) {
            float e = EXP2(c[rs][reg] * K2);
            rowacc[rs][reg] += (gibase + reg != gj) ? e : 0.f;
          }
        }
      } else {
        float coltmp = 0.f;
#pragma unroll
        for (int rs = 0; rs < 4; ++rs)
#pragma unroll
          for (int reg = 0; reg < 4; ++reg) {
            float e = EXP2(c[rs][reg] * K2);
            rowacc[rs][reg] += e;
            coltmp += e;
          }
        coltmp += __shfl_xor(coltmp, 16);
        coltmp += __shfl_xor(coltmp, 32);
        colacc[cs] = coltmp;
      }
    }

    // reduce rowacc across the 16 column-lanes
#pragma unroll
    for (int rs = 0; rs < 4; ++rs)
#pragma unroll
      for (int r = 0; r < 4; ++r) {
        float v = rowacc[rs][r];
        v += __shfl_xor(v, 1);
        v += __shfl_xor(v, 2);
        v += __shfl_xor(v, 4);
        v += __shfl_xor(v, 8);
        rowacc[rs][r] = v;
      }

    // cross-wave combine (phase 1 own, phase 2 partner adds)
    if (wx == 0 && l15 == 0) {
#pragma unroll
      for (int rs = 0; rs < 4; ++rs)
#pragma unroll
        for (int r = 0; r < 4; ++r)
          rowled[wy * 64 + rs * 16 + l4 * 4 + r] = rowacc[rs][r];
    }
    if (!isdiag && wy == 0 && l4 == 0) {
#pragma unroll
      for (int cs = 0; cs < 4; ++cs) colled[wx * 64 + cs * 16 + l15] = colacc[cs];
    }
    __syncthreads();
    if (wx == 1 && l15 == 0) {
#pragma unroll
      for (int rs = 0; rs < 4; ++rs)
#pragma unroll
        for (int r = 0; r < 4; ++r)
          rowled[wy * 64 + rs * 16 + l4 * 4 + r] += rowacc[rs][r];
    }
    if (!isdiag && wy == 1 && l4 == 0) {
#pragma unroll
      for (int cs = 0; cs < 4; ++cs) colled[wx * 64 + cs * 16 + l15] += colacc[cs];
    }
    __syncthreads();

    if (t < 128)
      partials[(size_t)jt * N_ROWS + ti * 128 + t] = rowled[t];
    else if (!isdiag)
      partials[(size_t)ti * N_ROWS + jt * 128 + (t - 128)] = colled[t - 128];
  }
}

// ---- Kernel 3: per-row lse term, grid-reduce via atomic (out pre-zeroed) ----
__global__ __launch_bounds__(256) void fin_kernel(
    const float* __restrict__ partials, const float* __restrict__ pos_buf,
    float* __restrict__ out) {
  const int row = blockIdx.x * 256 + threadIdx.x;
  float tot = 0.f;
#pragma unroll
  for (int k = 0; k < NT; ++k) tot += partials[(size_t)k * N_ROWS + row];
  float term = __logf(tot) - pos_buf[row];
#pragma unroll
  for (int off = 32; off > 0; off >>= 1) term += __shfl_xor(term, off);
  __shared__ float wsum[4];
  if ((threadIdx.x & 63) == 0) wsum[threadIdx.x >> 6] = term;
  __syncthreads();
  if (threadIdx.x == 0)
    atomicAdd(out, (wsum[0] + wsum[1] + wsum[2] + wsum[3]) * (1.0f / N_ROWS));
}

extern "C" void kernel_launch(void* const* d_in, const int* in_sizes, int n_in,
                              void* d_out, int out_size, void* d_ws, size_t ws_size,
                              hipStream_t stream) {
  const float* z_i = (const float*)d_in[0];
  const float* z_j = (const float*)d_in[1];
  float* out = (float*)d_out;

  ushort* Z = (ushort*)d_ws;                                        // 2 MB
  float* partials = (float*)((char*)d_ws + (size_t)N_ROWS * D * 2); // 2 MB
  float* pos_buf = partials + (size_t)NT * N_ROWS;                  // 32 KB

  hipLaunchKernelGGL(normalize_pos_kernel, dim3(B_ROWS / 4), dim3(256), 0,
                     stream, z_i, z_j, Z, pos_buf, out);
  hipLaunchKernelGGL(sim_kernel, dim3(SEGS, 32), dim3(256), 0, stream, Z,
                     partials);
  hipLaunchKernelGGL(fin_kernel, dim3(N_ROWS / 256), dim3(256), 0, stream,
                     partials, pos_buf, out);
}